// Round 10
// baseline (80.943 us; speedup 1.0000x reference)
//
#include <hip/hip_runtime.h>
#include <stdint.h>

// Problem constants
#define B_ 131072
#define T_ 8
#define C_ 32
#define H_ 4
#define D_ 8

#define NT 4      // tiles per wave
// per-wave HALF-slab: Q f32 [16 rows][32 dw, XOR-swizzled] = 2048 B
//                     K_T f16 [32 rows][32 B] = 1024 B; V_T same = 1024 B
#define QOFF 0
#define KOFF 2048
#define VOFF 3072
#define HSLAB 4096
// double-buffered: 2*HSLAB per wave -> 32768 B/block -> 5 blocks/CU

typedef _Float16 h16x2 __attribute__((ext_vector_type(2)));
typedef _Float16 f16x8 __attribute__((ext_vector_type(8)));
typedef float    f32x4 __attribute__((ext_vector_type(4)));
typedef __fp16   fp16x2 __attribute__((ext_vector_type(2)));  // cvt_pkrtz ret

union H2U { fp16x2 h; uint32_t u; };
union HW  { uint32_t u; h16x2 h; };
union F8U { f16x8 v; uint32_t u[4]; };

__device__ inline uint32_t pk(float lo, float hi) {
    H2U t; t.h = __builtin_amdgcn_cvt_pkrtz(lo, hi); return t.u;
}
__device__ inline h16x2 bch(uint32_t x) { HW t; t.u = x; return t.h; }

struct X2 { float4 a, b; };

// One wave = 16 rows (2 causal batches of T=8) per tile, NT tiles,
// software-pipelined across double-buffered wave-private slabs.
// Q stored f32 [16][32dw] with XOR swizzle col^=((row&7)<<2):
//   writes 2-way (free), reads bijective over (gg,cc&7) -> broadcast floor.
// K/V stored feature-major f16, bijective row permute p(f)=((f&3)<<3)|(f>>2).
// exp2-folded softmax (log2e in qscale). LDS wave-private: no barriers.
__global__ __launch_bounds__(256, 5) void attn_block_mfma(
    const float* __restrict__ X,
    const float* __restrict__ Wq,
    const float* __restrict__ Wk,
    const float* __restrict__ Wv,
    const float* __restrict__ Wf,
    const float* __restrict__ bfb,
    float* __restrict__ Y)
{
    __shared__ __align__(16) char ldsraw[4][2][HSLAB];
    const int wid  = threadIdx.x >> 6;
    const int lane = threadIdx.x & 63;
    const int cc = lane & 15;   // C-frag col; attention row t
    const int gg = lane >> 4;   // k-group; attention head
    char* base = &ldsraw[wid][0][0];

    // 1/sqrt(D) * log2(e): exp(x) = exp2(x*log2e), folded into Wq
    const float qscale = 0.35355339059327373f * 1.4426950408889634f;

    // ---------- preamble: weight B-frags (f16) ----------
    f16x8 bW[6];   // 0,1=q  2,3=k  4,5=v   (B-frag: col=lane&15, k=gg*8+j)
    {
        const float* const Ws[3] = { Wq, Wk, Wv };
        #pragma unroll
        for (int tau = 0; tau < 6; ++tau) {
            const float* Wm = Ws[tau >> 1];
            const int col = (tau & 1) * 16 + cc;
            const int head = col >> 3, d = col & 7;
            #pragma unroll
            for (int j = 0; j < 8; ++j) {
                float f = Wm[head * (C_ * D_) + (gg * 8 + j) * D_ + d];
                if (tau < 2) f *= qscale;
                bW[tau][j] = (_Float16)f;
            }
        }
    }
    f16x8 bF[2];   // FF weights
    {
        #pragma unroll
        for (int tau = 0; tau < 2; ++tau) {
            const int col = tau * 16 + cc;
            #pragma unroll
            for (int j = 0; j < 8; ++j)
                bF[tau][j] = (_Float16)Wf[(gg * 8 + j) * C_ + col];
        }
    }
    const float bias0 = bfb[cc];
    const float bias1 = bfb[cc + 16];

    const int tilebase = (blockIdx.x * 4 + wid) * (16 * NT);
    const f32x4 z = { 0.f, 0.f, 0.f, 0.f };

    auto ldx = [&](int it) {
        const float* p = X + (size_t)(tilebase + it * 16 + cc) * C_ + gg * 8;
        X2 r; r.a = *(const float4*)p; r.b = *(const float4*)(p + 4); return r;
    };

    // stage: QKV projection for one tile into slab `slot`
    auto stage = [&](int slot, X2 x) {
        f16x8 aX;   // A-frag from X: row = lane&15, k = gg*8+j
        aX[0] = (_Float16)x.a.x; aX[1] = (_Float16)x.a.y;
        aX[2] = (_Float16)x.a.z; aX[3] = (_Float16)x.a.w;
        aX[4] = (_Float16)x.b.x; aX[5] = (_Float16)x.b.y;
        aX[6] = (_Float16)x.b.z; aX[7] = (_Float16)x.b.w;

        f32x4 cq[6];
        #pragma unroll
        for (int tau = 0; tau < 6; ++tau)
            cq[tau] = __builtin_amdgcn_mfma_f32_16x16x32_f16(aX, bW[tau], z, 0, 0, 0);

        char* b2 = base + slot * HSLAB;
        float* qb = (float*)(b2 + QOFF);
        // Q -> f32 [16][32dw], swizzled col' = col ^ ((row&7)<<2)
        #pragma unroll
        for (int tau = 0; tau < 2; ++tau)
            #pragma unroll
            for (int r = 0; r < 4; ++r) {
                const int row = gg * 4 + r;
                const int colp = (tau * 16 + cc) ^ ((row & 7) << 2);
                qb[row * 32 + colp] = cq[tau][r];
            }
        // K,V -> packed f16 feature-major; row p(f) = ((f&3)<<3)|(f>>2),
        // f = (tau&1)*16+cc  ->  p = (cc&3)*8 + (tau&1)*4 + (cc>>2)
        #pragma unroll
        for (int tau = 2; tau < 6; ++tau) {
            char* dst = b2 + ((tau < 4) ? KOFF : VOFF);
            const int p = (cc & 3) * 8 + (tau & 1) * 4 + (cc >> 2);
            uint2 w2;
            w2.x = pk(cq[tau][0], cq[tau][1]);
            w2.y = pk(cq[tau][2], cq[tau][3]);
            *(uint2*)(dst + p * 32 + gg * 8) = w2;
        }
    };

    // attn + FF + store for one tile from slab `slot`
    auto attn = [&](int slot, int it) {
        char* b2 = base + slot * HSLAB;
        const float* qb = (const float*)(b2 + QOFF);
        const char*  kb = b2 + KOFF;
        const char*  vb = b2 + VOFF;
        const int tpos = cc & 7, bb = cc >> 3;

        // Q read: row cc, dw blocks (gg*8+4b) ^ ((cc&7)<<2), b=0,1
        const int swz = (cc & 7) << 2;
        const float4 qa = *(const float4*)(qb + cc * 32 + ((gg * 8) ^ swz));
        const float4 qv = *(const float4*)(qb + cc * 32 + ((gg * 8 + 4) ^ swz));
        uint32_t qp[8];
        qp[0] = pk(qa.x, qa.x); qp[1] = pk(qa.y, qa.y);
        qp[2] = pk(qa.z, qa.z); qp[3] = pk(qa.w, qa.w);
        qp[4] = pk(qv.x, qv.x); qp[5] = pk(qv.y, qv.y);
        qp[6] = pk(qv.z, qv.z); qp[7] = pk(qv.w, qv.w);

        // scores: K_T row for f = gg*8+j is p = ((j&3)<<3)|(gg*2)|(j>>2);
        // 8 distinct addrs/inst, broadcast over 8 lanes
        h16x2 s01 = { (_Float16)0, (_Float16)0 };
        h16x2 s23 = s01, s45 = s01, s67 = s01;
        #pragma unroll
        for (int j = 0; j < 8; ++j) {
            const int p = ((j & 3) << 3) | (gg * 2) | (j >> 2);
            const uint4 ku = *(const uint4*)(kb + p * 32 + bb * 16);
            const h16x2 qj = bch(qp[j]);
            s01 += qj * bch(ku.x);
            s23 += qj * bch(ku.y);
            s45 += qj * bch(ku.z);
            s67 += qj * bch(ku.w);
        }
        float sc[8];
        sc[0] = (float)s01[0]; sc[1] = (float)s01[1];
        sc[2] = (float)s23[0]; sc[3] = (float)s23[1];
        sc[4] = (float)s45[0]; sc[5] = (float)s45[1];
        sc[6] = (float)s67[0]; sc[7] = (float)s67[1];
        #pragma unroll
        for (int s = 0; s < 8; ++s)
            if (s > tpos) sc[s] = -1.0e30f;

        float m = sc[0];
        #pragma unroll
        for (int s = 1; s < 8; ++s) m = fmaxf(m, sc[s]);
        float e[8], sum = 0.f;
        #pragma unroll
        for (int s = 0; s < 8; ++s) { e[s] = exp2f(sc[s] - m); sum += e[s]; }
        const float winv = 1.0f / sum;

        uint32_t wp[4];
        wp[0] = pk(e[0] * winv, e[1] * winv);
        wp[1] = pk(e[2] * winv, e[3] * winv);
        wp[2] = pk(e[4] * winv, e[5] * winv);
        wp[3] = pk(e[6] * winv, e[7] * winv);
        const h16x2 w0 = bch(wp[0]), w1 = bch(wp[1]);
        const h16x2 w2 = bch(wp[2]), w3 = bch(wp[3]);

        float o[8];
        #pragma unroll
        for (int d = 0; d < 8; ++d) {
            const int p = ((d & 3) << 3) | (gg * 2) | (d >> 2);
            const uint4 vu = *(const uint4*)(vb + p * 32 + bb * 16);
            h16x2 acc = w0 * bch(vu.x);
            acc += w1 * bch(vu.y);
            acc += w2 * bch(vu.z);
            acc += w3 * bch(vu.w);
            o[d] = (float)acc[0] + (float)acc[1];
        }

        // FF: A-frag from o (row=cc, k=gg*8+j)
        F8U aO;
        aO.u[0] = pk(o[0], o[1]);
        aO.u[1] = pk(o[2], o[3]);
        aO.u[2] = pk(o[4], o[5]);
        aO.u[3] = pk(o[6], o[7]);

        const f32x4 y0 = __builtin_amdgcn_mfma_f32_16x16x32_f16(aO.v, bF[0], z, 0, 0, 0);
        const f32x4 y1 = __builtin_amdgcn_mfma_f32_16x16x32_f16(aO.v, bF[1], z, 0, 0, 0);

        const int rowbase = tilebase + it * 16;
        #pragma unroll
        for (int r = 0; r < 4; ++r) {
            float* yp = Y + (size_t)(rowbase + gg * 4 + r) * C_;
            yp[cc]      = fmaxf(y0[r] + bias0, 0.f);
            yp[cc + 16] = fmaxf(y1[r] + bias1, 0.f);
        }
    };

    // ---- explicit software pipeline (NT = 4) ----
    X2 x0 = ldx(0), x1 = ldx(1), x2 = ldx(2), x3 = ldx(3);
    stage(0, x0);
    stage(1, x1);
    attn(0, 0);
    stage(0, x2);
    attn(1, 1);
    stage(1, x3);
    attn(0, 2);
    attn(1, 3);
}

extern "C" void kernel_launch(void* const* d_in, const int* in_sizes, int n_in,
                              void* d_out, int out_size, void* d_ws, size_t ws_size,
                              hipStream_t stream)
{
    const float* X  = (const float*)d_in[0];
    const float* Wq = (const float*)d_in[1];
    const float* Wk = (const float*)d_in[2];
    const float* Wv = (const float*)d_in[3];
    const float* Wf = (const float*)d_in[4];
    const float* bf = (const float*)d_in[5];
    float* Y = (float*)d_out;

    const int rows = B_ * T_;                 // 1,048,576
    const int rows_per_block = 4 * NT * 16;   // 256
    dim3 grid(rows / rows_per_block), block(256);
    hipLaunchKernelGGL(attn_block_mfma, grid, block, 0, stream,
                       X, Wq, Wk, Wv, Wf, bf, Y);
}